// Round 10
// baseline (119.051 us; speedup 1.0000x reference)
//
#include <hip/hip_runtime.h>
#include <hip/hip_bf16.h>

// Problem constants (B,N,E,H,D) = (2,2048,1024,16,64)
#define B_ 2
#define N_ 2048
#define E_ 1024
#define H_ 16
#define D_ 64
#define M_ 4096      // B*N
#define HD_ 1024     // H*D
#define NT_ 3072     // 3*H*D

using f32x4  = __attribute__((ext_vector_type(4))) float;
using f32x16 = __attribute__((ext_vector_type(16))) float;
using bf16x8 = __attribute__((ext_vector_type(8))) short;

static __device__ __forceinline__ unsigned short f2bf(float f) {
  union { float f; unsigned u; } v; v.f = f;
  unsigned r = v.u + 0x7FFF + ((v.u >> 16) & 1);   // RNE
  return (unsigned short)(r >> 16);
}
static __device__ __forceinline__ float bf2f(short s) {
  union { unsigned u; float f; } v; v.u = ((unsigned)(unsigned short)s) << 16; return v.f;
}

// async global->LDS, 16B per lane. LDS dest = wave-uniform base + lane*16.
// Global SOURCE is per-lane -> swizzled LDS layouts via pre-swizzled source.
static __device__ __forceinline__ void gld16(const void* g, void* l) {
  __builtin_amdgcn_global_load_lds(
      (const __attribute__((address_space(1))) unsigned int*)g,
      (__attribute__((address_space(3))) unsigned int*)l, 16, 0, 0);
}

// v_cvt_pk_bf16_f32: D[15:0]=bf16(lo), D[31:16]=bf16(hi)
static __device__ __forceinline__ unsigned cvtpk(float lo, float hi) {
  unsigned r;
  asm("v_cvt_pk_bf16_f32 %0, %1, %2" : "=v"(r) : "v"(lo), "v"(hi));
  return r;
}
// v_permlane32_swap_b32: a.hi-lanes <-> b.lo-lanes
static __device__ __forceinline__ void pl32swap(unsigned& a, unsigned& b) {
  asm("v_permlane32_swap_b32 %0, %1" : "+v"(a), "+v"(b));
}

// gemm LDS sub-chunk swizzle (16B units within a 64B row)
static __device__ __forceinline__ int gswz(int row) {
  return ((row >> 1) & 3) ^ ((row >> 3) & 1);
}

// ---------------- conversion kernels ----------------

__global__ void k_cvt_x(const float* __restrict__ x, unsigned short* __restrict__ xb) {
  int t = blockIdx.x * 256 + threadIdx.x;          // one float4 per thread
  float4 v = reinterpret_cast<const float4*>(x)[t];
  ushort4 o;
  o.x = f2bf(v.x); o.y = f2bf(v.y); o.z = f2bf(v.z); o.w = f2bf(v.w);
  reinterpret_cast<ushort4*>(xb)[t] = o;
}

// Wqkv rows are interleaved (h, d, kind): rin = h*192 + d*3 + kind.
// Output row r = kind*1024 + h*64 + d.
// Q rows (kind==0) pre-scaled by (1/8)*log2(e) so attention can use exp2.
__global__ void k_cvt_wqkv(const float* __restrict__ w, const float* __restrict__ bsrc,
                           unsigned short* __restrict__ wb, float* __restrict__ br) {
  int t = blockIdx.x * 256 + threadIdx.x;
  int r = t >> 8;                 // 0..3071
  int c = (t & 255) * 4;
  int kind = r >> 10, hd = r & 1023;
  int h = hd >> 6, d = hd & 63;
  int rin = h * 192 + d * 3 + kind;
  float s = (kind == 0) ? 0.125f * 1.4426950408889634f : 1.0f;
  float4 v = *reinterpret_cast<const float4*>(w + (size_t)rin * E_ + c);
  ushort4 o;
  o.x = f2bf(v.x * s); o.y = f2bf(v.y * s); o.z = f2bf(v.z * s); o.w = f2bf(v.w * s);
  *reinterpret_cast<ushort4*>(wb + (size_t)r * E_ + c) = o;
  if (c == 0) br[r] = bsrc[rin] * s;
}

__global__ void k_cvt_wout(const float* __restrict__ w, unsigned short* __restrict__ wb) {
  int t = blockIdx.x * 256 + threadIdx.x;
  int r = t >> 8;
  int c = (t & 255) * 4;
  float4 v = *reinterpret_cast<const float4*>(w + (size_t)r * HD_ + c);
  ushort4 o;
  o.x = f2bf(v.x); o.y = f2bf(v.y); o.z = f2bf(v.z); o.w = f2bf(v.w);
  *reinterpret_cast<ushort4*>(wb + (size_t)r * HD_ + c) = o;
}

// ---------------- V transpose: [bh][n][d] -> [bh][d][n], LDS-tiled ----------------
__global__ void k_vt(const unsigned short* __restrict__ Vr,
                     unsigned short* __restrict__ Vt) {
  __shared__ unsigned short tile[64][68];   // +4 pad breaks bank alignment
  int bh = blockIdx.x & 31;
  int nt = blockIdx.x >> 5;                 // 0..31
  int t = threadIdx.x;
  int r = t >> 3, c8 = (t & 7) * 8;
#pragma unroll
  for (int h = 0; h < 2; ++h) {
    bf16x8 v = *reinterpret_cast<const bf16x8*>(
        Vr + ((size_t)bh * N_ + nt * 64 + r + h * 32) * D_ + c8);
#pragma unroll
    for (int j = 0; j < 8; ++j) tile[r + h * 32][c8 + j] = (unsigned short)v[j];
  }
  __syncthreads();
#pragma unroll
  for (int h = 0; h < 2; ++h) {
    int d = (t >> 3) + h * 32;
    int n0 = (t & 7) * 8;
    bf16x8 o;
#pragma unroll
    for (int j = 0; j < 8; ++j) o[j] = (short)tile[n0 + j][d];
    *reinterpret_cast<bf16x8*>(Vt + ((size_t)bh * D_ + d) * N_ + nt * 64 + n0) = o;
  }
}

// ---------------- GEMM: C[m][n] = sum_k A[m][k]*W[n][k] + bias[n] ----------------
// Paired-tile pipeline: 4 LDS buffers; per period stage 2 K-tiles, counted
// vmcnt (2 tiles in flight), raw barriers, compute 2 K-tiles (2 indep chains).
// V epilogue now COALESCED [b][h][n][d] (transpose done by k_vt afterwards).
template <int EPI, int BM>
__global__ __launch_bounds__(256, 2) void k_gemm(
    const unsigned short* __restrict__ A,   // [M][K] bf16
    const unsigned short* __restrict__ W,   // [Nt][K] bf16
    const float* __restrict__ bias,         // [Nt]
    unsigned short* __restrict__ Qo, unsigned short* __restrict__ Ko,
    unsigned short* __restrict__ Vo, float* __restrict__ Fo,
    int M, int Nt, int K)
{
  constexpr int APT = (BM == 128) ? 2 : 1;   // A gld16 per thread per tile
  constexpr int LPI = APT + 2;               // loads per thread per tile
  constexpr int NF  = (BM == 128) ? 4 : 2;   // n-frags per wave
  __shared__ unsigned short As[4][BM * 32];
  __shared__ unsigned short Bs[4][128 * 32];
  const int t = threadIdx.x;
  const int w = t >> 6, l = t & 63, lg = l >> 4, lr = l & 15;
  const int wrow0 = (BM == 128) ? (w >> 1) * 64 : 0;
  const int wcol0 = (BM == 128) ? (w & 1) * 64 : w * 32;
  const int row0 = blockIdx.x * BM, col0 = blockIdx.y * 128;
  const int NT = K >> 5;

  f32x4 acc[4][NF] = {};

  auto stage = [&](int b, int k0) {
#pragma unroll
    for (int c = 0; c < APT; ++c) {
      int ci = w * APT + c;
      int row = ci * 16 + (l >> 2);
      int sub = (l & 3) ^ gswz(row);
      gld16(A + (size_t)(row0 + row) * K + k0 + sub * 8,
            (unsigned short*)&As[b][0] + ci * 512);
    }
#pragma unroll
    for (int c = 0; c < 2; ++c) {
      int ci = w * 2 + c;
      int row = ci * 16 + (l >> 2);
      int sub = (l & 3) ^ gswz(row);
      gld16(W + (size_t)(col0 + row) * K + k0 + sub * 8,
            (unsigned short*)&Bs[b][0] + ci * 512);
    }
  };

  auto compute = [&](int ib) {
    bf16x8 af[4], bf[NF];
#pragma unroll
    for (int m = 0; m < 4; ++m) {
      int row = wrow0 + m * 16 + lr;
      af[m] = *reinterpret_cast<const bf16x8*>(
          &As[ib][row * 32 + ((lg ^ gswz(row)) * 8)]);
    }
#pragma unroll
    for (int n = 0; n < NF; ++n) {
      int row = wcol0 + n * 16 + lr;
      bf[n] = *reinterpret_cast<const bf16x8*>(
          &Bs[ib][row * 32 + ((lg ^ gswz(row)) * 8)]);
    }
    __builtin_amdgcn_s_setprio(1);
#pragma unroll
    for (int m = 0; m < 4; ++m)
#pragma unroll
      for (int n = 0; n < NF; ++n)
        acc[m][n] = __builtin_amdgcn_mfma_f32_16x16x32_bf16(af[m], bf[n], acc[m][n], 0, 0, 0);
    __builtin_amdgcn_s_setprio(0);
  };

  stage(0, 0);
  stage(1, 32);
  const int NP = NT >> 1;
  for (int p = 0; p < NP; ++p) {
    const int t0 = 2 * p;
    if (t0 + 2 < NT) {
      stage((t0 + 2) & 3, (t0 + 2) * 32);
      stage((t0 + 3) & 3, (t0 + 3) * 32);
      if constexpr (LPI == 4) asm volatile("s_waitcnt vmcnt(8)" ::: "memory");
      else                    asm volatile("s_waitcnt vmcnt(6)" ::: "memory");
    } else {
      asm volatile("s_waitcnt vmcnt(0)" ::: "memory");
    }
    asm volatile("s_barrier" ::: "memory");
    compute(t0 & 3);
    compute((t0 + 1) & 3);
    asm volatile("s_barrier" ::: "memory");
  }

#pragma unroll
  for (int m = 0; m < 4; ++m) {
#pragma unroll
    for (int n = 0; n < NF; ++n) {
      int col = col0 + wcol0 + n * 16 + lr;
      float bb = bias[col];
#pragma unroll
      for (int rr = 0; rr < 4; ++rr) {
        int ro = row0 + wrow0 + m * 16 + lg * 4 + rr;
        float val = acc[m][n][rr] + bb;
        if (EPI == 0) {
          int kind = col >> 10, hd = col & 1023, h = hd >> 6, d = hd & 63;
          int bi = ro >> 11, ni = ro & 2047;     // token -> (b, n)
          unsigned short bv = f2bf(val);
          size_t bh = (size_t)(bi * H_ + h);
          if (kind == 0)      Qo[(bh * N_ + ni) * D_ + d] = bv;
          else if (kind == 1) Ko[(bh * N_ + ni) * D_ + d] = bv;
          else                Vo[(bh * N_ + ni) * D_ + d] = bv;   // coalesced; k_vt transposes
        } else {
          Fo[(size_t)ro * HD_ + col] = val;
        }
      }
    }
  }
}

// ---------------- flash attention (swapped 32x32 MFMA + 3-buffer pipeline) ----------------
// Unchanged from R9 (counted vmcnt, raw barriers, no-max softmax).
__global__ __launch_bounds__(256, 3) void k_attn(
    const unsigned short* __restrict__ Q,
    const unsigned short* __restrict__ Kg,
    const unsigned short* __restrict__ Vg,
    unsigned short* __restrict__ O,
    unsigned short* __restrict__ Pp,    // [bh][16][128][64] bf16 partial O~
    float* __restrict__ Pml)            // [bh][16][128]  l
{
  static const int u_qt[24] = {15,15,14,13,12,11,10, 9,   8, 7,14, 6,13, 5,12, 4,   8, 0, 9, 1,10, 2,11, 3};
  static const int u_t0[24] = { 0,16, 0, 0, 0, 0, 0, 0,   0, 0,16, 0,16, 0,16, 0,  16, 0,16, 0,16, 0,16, 0};
  static const int u_ps[24] = {14,15,12,10, 8, 6, 4, 2,   0,-1,13,-1,11,-1, 9,-1,   1,-1, 3,-1, 5,-1, 7,-1};

  __shared__ unsigned short Ks[3][64 * 64];   // [kv][k], swizzled rows
  __shared__ unsigned short Vs[3][64 * 64];   // [d][kv], swizzled rows

  const int t = threadIdx.x;
  const int w = t >> 6, l = t & 63;
  const int lq = l & 31;
  const int hi = l >> 5;
  const int bh = blockIdx.x & 31;
  const int u  = blockIdx.x >> 5;
  const int qt = u_qt[u], t0 = u_t0[u], ps = u_ps[u];
  const int q0 = qt * 128;
  const int r0w = q0 + w * 32;
  const int rtop = r0w + 31;
  const bool splitc0 = (ps >= 0) && (t0 == 0);
  const int tendW = splitc0 ? 16 : ((rtop >> 6) + 1);
  const int tendB = splitc0 ? 16 : (((q0 + 127) >> 6) + 1);

  const unsigned short* Qb = Q  + (size_t)bh * (N_ * D_);
  const unsigned short* Kb = Kg + (size_t)bh * (N_ * D_);
  const unsigned short* Vb = Vg + (size_t)bh * (N_ * D_);   // [d][n]

  const int pr  = l >> 3;
  const int pswz = ((l & 7) ^ pr) * 8;
  const unsigned short* KsrcB = Kb + pr * D_ + pswz;
  const unsigned short* VsrcB = Vb + pr * N_ + pswz;

  bf16x8 qf[4];
#pragma unroll
  for (int ks = 0; ks < 4; ++ks)
    qf[ks] = *reinterpret_cast<const bf16x8*>(
        Qb + (size_t)(r0w + lq) * D_ + ks * 16 + hi * 8);

  f32x16 oacc[2] = {};
  float lrun = 0.f;

  auto stage = [&](int b, int kt_) {
    const int kv = kt_ * 64;
#pragma unroll
    for (int c = 0; c < 2; ++c) {
      int cb = w * 2 + c;
      gld16(KsrcB + kv * D_ + cb * 512, (unsigned short*)&Ks[b][0] + cb * 512);
      gld16(VsrcB + kv + cb * 8 * N_,   (unsigned short*)&Vs[b][0] + cb * 512);
    }
  };

  stage(0, t0);
  if (t0 + 1 < tendB) stage(1, t0 + 1);

  for (int kt = t0; kt < tendB; ++kt) {
    const int ib = (kt - t0) % 3;
    if (kt + 2 < tendB) stage((kt - t0 + 2) % 3, kt + 2);
    const int na = tendB - 1 - kt;
    if (na >= 2)      asm volatile("s_waitcnt vmcnt(8)" ::: "memory");
    else if (na == 1) asm volatile("s_waitcnt vmcnt(4)" ::: "memory");
    else              asm volatile("s_waitcnt vmcnt(0)" ::: "memory");
    asm volatile("s_barrier" ::: "memory");

    if (kt < tendW) {
      const int kv0 = kt * 64;
      bf16x8 kf[2][4], vf[2][4];
#pragma unroll
      for (int ct = 0; ct < 2; ++ct)
#pragma unroll
        for (int ks = 0; ks < 4; ++ks) {
          int row = ct * 32 + lq;
          kf[ct][ks] = *reinterpret_cast<const bf16x8*>(
              &Ks[ib][row * 64 + (((ks * 2 + hi) ^ (lq & 7)) * 8)]);
        }
#pragma unroll
      for (int dt = 0; dt < 2; ++dt)
#pragma unroll
        for (int j = 0; j < 4; ++j) {
          int row = dt * 32 + lq;
          vf[dt][j] = *reinterpret_cast<const bf16x8*>(
              &Vs[ib][row * 64 + (((j * 2 + hi) ^ (lq & 7)) * 8)]);
        }

      f32x16 sct[2];
      __builtin_amdgcn_s_setprio(1);
#pragma unroll
      for (int ct = 0; ct < 2; ++ct) {
        f32x16 z = {};
#pragma unroll
        for (int ks = 0; ks < 4; ++ks)
          z = __builtin_amdgcn_mfma_f32_32x32x16_bf16(kf[ct][ks], qf[ks], z, 0, 0, 0);
        sct[ct] = z;
      }
      __builtin_amdgcn_s_setprio(0);

      if (kv0 + 63 > r0w) {
        int qrow = r0w + lq;
#pragma unroll
        for (int ct = 0; ct < 2; ++ct)
#pragma unroll
          for (int r = 0; r < 16; ++r) {
            int kv = kv0 + ct * 32 + (r & 3) + 8 * (r >> 2) + 4 * hi;
            if (kv > qrow) sct[ct][r] = -1e30f;
          }
      }

      float s16[16];
#pragma unroll
      for (int r = 0; r < 16; ++r) {
        float p0 = exp2f(sct[0][r]);
        float p1 = exp2f(sct[1][r]);
        sct[0][r] = p0; sct[1][r] = p1;
        s16[r] = p0 + p1;
      }
#pragma unroll
      for (int st = 8; st >= 1; st >>= 1)
#pragma unroll
        for (int r = 0; r < 8; ++r)
          if (r < st) s16[r] += s16[r + st];
      lrun += s16[0] + __shfl_xor(s16[0], 32);

      bf16x8 paf[4];
#pragma unroll
      for (int ct = 0; ct < 2; ++ct) {
        unsigned u0 = cvtpk(sct[ct][0],  sct[ct][1]);
        unsigned u1 = cvtpk(sct[ct][2],  sct[ct][3]);
        unsigned u2 = cvtpk(sct[ct][4],  sct[ct][5]);
        unsigned u3 = cvtpk(sct[ct][6],  sct[ct][7]);
        unsigned u4 = cvtpk(sct[ct][8],  sct[ct][9]);
        unsigned u5 = cvtpk(sct[ct][10], sct[ct][11]);
        unsigned u6 = cvtpk(sct[ct][12], sct[ct][13]);
        unsigned u7 = cvtpk(sct[ct][14], sct[ct][15]);
        pl32swap(u0, u2); pl32swap(u1, u3);
        pl32swap(u4, u6); pl32swap(u5, u7);
        union { unsigned uu[4]; bf16x8 v; } c0, c1;
        c0.uu[0] = u0; c0.uu[1] = u1; c0.uu[2] = u2; c0.uu[3] = u3;
        c1.uu[0] = u4; c1.uu[1] = u5; c1.uu[2] = u6; c1.uu[3] = u7;
        paf[ct * 2]     = c0.v;
        paf[ct * 2 + 1] = c1.v;
      }

      __builtin_amdgcn_s_setprio(1);
#pragma unroll
      for (int dt = 0; dt < 2; ++dt)
#pragma unroll
        for (int j = 0; j < 4; ++j)
          oacc[dt] = __builtin_amdgcn_mfma_f32_32x32x16_bf16(paf[j], vf[dt][j], oacc[dt], 0, 0, 0);
      __builtin_amdgcn_s_setprio(0);
    }

    asm volatile("s_barrier" ::: "memory");
  }

  int bi = bh >> 4, h = bh & 15;
  if (ps < 0) {
    float inv = 1.0f / lrun;
    float iv[16];
#pragma unroll
    for (int r = 0; r < 16; ++r)
      iv[r] = __shfl(inv, (r & 3) + 8 * (r >> 2) + 4 * hi);
#pragma unroll
    for (int dt = 0; dt < 2; ++dt)
#pragma unroll
      for (int r = 0; r < 16; ++r) {
        int qr = r0w + (r & 3) + 8 * (r >> 2) + 4 * hi;
        int d = dt * 32 + lq;
        O[((size_t)(bi * N_ + qr) * H_ + h) * D_ + d] = f2bf(oacc[dt][r] * iv[r]);
      }
  } else {
    unsigned short* pb = Pp + (size_t)(bh * 16 + ps) * (128 * 64);
    float* mb = Pml + (size_t)(bh * 16 + ps) * 128;
#pragma unroll
    for (int dt = 0; dt < 2; ++dt)
#pragma unroll
      for (int r = 0; r < 16; ++r) {
        int rloc = w * 32 + (r & 3) + 8 * (r >> 2) + 4 * hi;
        pb[rloc * 64 + dt * 32 + lq] = f2bf(oacc[dt][r]);
      }
    if (l < 32) {
      int rloc = w * 32 + l;
      mb[rloc] = lrun;
    }
  }
}

// ---------------- merge the two kv-chunk partials for q0>=1024 tiles ----------------
__global__ void k_merge(const unsigned short* __restrict__ Pp,
                        const float* __restrict__ Pml,
                        unsigned short* __restrict__ O) {
  int t = blockIdx.x * 256 + threadIdx.x;   // 262144 threads
  int dseg = t & 7;
  int rloc = (t >> 3) & 127;
  int qt8 = (t >> 10) & 7;
  int bh  = t >> 13;
  size_t b0 = (size_t)(bh * 16 + qt8 * 2) * 128 + rloc;
  size_t b1 = b0 + 128;
  bf16x8 o0 = *reinterpret_cast<const bf16x8*>(Pp + b0 * 64 + dseg * 8);
  bf16x8 o1 = *reinterpret_cast<const bf16x8*>(Pp + b1 * 64 + dseg * 8);
  float l0 = Pml[b0], l1 = Pml[b1];
  float inv = 1.0f / (l0 + l1);
  int n = (qt8 + 8) * 128 + rloc;
  int bi = bh >> 4, h = bh & 15;
  unsigned short* op = O + ((size_t)(bi * N_ + n) * H_ + h) * D_ + dseg * 8;
  bf16x8 res;
#pragma unroll
  for (int j = 0; j < 8; ++j)
    res[j] = (short)f2bf((bf2f(o0[j]) + bf2f(o1[j])) * inv);
  *reinterpret_cast<bf16x8*>(op) = res;
}

// ---------------- launch ----------------

extern "C" void kernel_launch(void* const* d_in, const int* in_sizes, int n_in,
                              void* d_out, int out_size, void* d_ws, size_t ws_size,
                              hipStream_t stream) {
  const float* x    = (const float*)d_in[0];
  const float* Wqkv = (const float*)d_in[1];
  const float* bqkv = (const float*)d_in[2];
  const float* Wout = (const float*)d_in[3];
  const float* bout = (const float*)d_in[4];
  float* out = (float*)d_out;

  char* ws = (char*)d_ws;
  unsigned short* xb  = (unsigned short*)ws; ws += (size_t)M_ * E_ * 2;       // 8 MB
  unsigned short* wqb = (unsigned short*)ws; ws += (size_t)NT_ * E_ * 2;      // 6 MB
  float*          bqr = (float*)ws;          ws += 16384;                     // 16 KB
  unsigned short* wob = (unsigned short*)ws; ws += (size_t)E_ * HD_ * 2;      // 2 MB
  unsigned short* Qb  = (unsigned short*)ws; ws += (size_t)M_ * D_ * H_ * 2;  // 8 MB
  unsigned short* Kb  = (unsigned short*)ws; ws += (size_t)M_ * D_ * H_ * 2;  // 8 MB
  unsigned short* Vb  = (unsigned short*)ws; ws += (size_t)M_ * D_ * H_ * 2;  // 8 MB
  unsigned short* ao  = (unsigned short*)ws; ws += (size_t)M_ * HD_ * 2;      // 8 MB

  // Buffer lifetime plan:
  //   gemm0 writes V RAW (coalesced [b][h][n][d]) into the ao region (dead now).
  //   k_vt transposes ao -> Vb ([b][h][d][n]).  attn reads Qb/Kb/Vb, writes ao.
  //   Attention partials alias xb (Pp) and wqb (Pml) - dead after gemm0.
  unsigned short* Vraw = ao;
  unsigned short* Pp  = xb;            // 32*16*128*64 bf16 = 8 MB
  float*          Pml = (float*)wqb;   // 32*16*128 f32 = 256 KB

  k_cvt_x<<<(M_ * E_) / 4 / 256, 256, 0, stream>>>(x, xb);
  k_cvt_wqkv<<<NT_, 256, 0, stream>>>(Wqkv, bqkv, wqb, bqr);
  k_cvt_wout<<<E_, 256, 0, stream>>>(Wout, wob);

  k_gemm<0, 128><<<dim3(M_ / 128, NT_ / 128), 256, 0, stream>>>(
      xb, wqb, bqr, Qb, Kb, Vraw, nullptr, M_, NT_, E_);

  k_vt<<<1024, 256, 0, stream>>>(Vraw, Vb);

  k_attn<<<768, 256, 0, stream>>>(Qb, Kb, Vb, ao, Pp, Pml);
  k_merge<<<1024, 256, 0, stream>>>(Pp, Pml, ao);

  k_gemm<1, 64><<<dim3(M_ / 64, HD_ / 128), 256, 0, stream>>>(
      ao, wob, bout, nullptr, nullptr, nullptr, out, M_, HD_, E_);
}

// Round 11
// 118.165 us; speedup vs baseline: 1.0075x; 1.0075x over previous
//
#include <hip/hip_runtime.h>
#include <hip/hip_bf16.h>

// Problem constants (B,N,E,H,D) = (2,2048,1024,16,64)
#define B_ 2
#define N_ 2048
#define E_ 1024
#define H_ 16
#define D_ 64
#define M_ 4096      // B*N
#define HD_ 1024     // H*D
#define NT_ 3072     // 3*H*D

using f32x4  = __attribute__((ext_vector_type(4))) float;
using f32x16 = __attribute__((ext_vector_type(16))) float;
using bf16x8 = __attribute__((ext_vector_type(8))) short;

static __device__ __forceinline__ unsigned short f2bf(float f) {
  union { float f; unsigned u; } v; v.f = f;
  unsigned r = v.u + 0x7FFF + ((v.u >> 16) & 1);   // RNE
  return (unsigned short)(r >> 16);
}
static __device__ __forceinline__ float bf2f(short s) {
  union { unsigned u; float f; } v; v.u = ((unsigned)(unsigned short)s) << 16; return v.f;
}

// async global->LDS, 16B per lane. LDS dest = wave-uniform base + lane*16.
// Global SOURCE is per-lane -> swizzled LDS layouts via pre-swizzled source.
static __device__ __forceinline__ void gld16(const void* g, void* l) {
  __builtin_amdgcn_global_load_lds(
      (const __attribute__((address_space(1))) unsigned int*)g,
      (__attribute__((address_space(3))) unsigned int*)l, 16, 0, 0);
}

// v_cvt_pk_bf16_f32: D[15:0]=bf16(lo), D[31:16]=bf16(hi)
static __device__ __forceinline__ unsigned cvtpk(float lo, float hi) {
  unsigned r;
  asm("v_cvt_pk_bf16_f32 %0, %1, %2" : "=v"(r) : "v"(lo), "v"(hi));
  return r;
}
// v_permlane32_swap_b32: a.hi-lanes <-> b.lo-lanes
static __device__ __forceinline__ void pl32swap(unsigned& a, unsigned& b) {
  asm("v_permlane32_swap_b32 %0, %1" : "+v"(a), "+v"(b));
}

// gemm LDS sub-chunk swizzle (16B units within a 64B row)
static __device__ __forceinline__ int gswz(int row) {
  return ((row >> 1) & 3) ^ ((row >> 3) & 1);
}

// ---------------- conversion kernels ----------------

__global__ void k_cvt_x(const float* __restrict__ x, unsigned short* __restrict__ xb) {
  int t = blockIdx.x * 256 + threadIdx.x;          // one float4 per thread
  float4 v = reinterpret_cast<const float4*>(x)[t];
  ushort4 o;
  o.x = f2bf(v.x); o.y = f2bf(v.y); o.z = f2bf(v.z); o.w = f2bf(v.w);
  reinterpret_cast<ushort4*>(xb)[t] = o;
}

// Wqkv rows are interleaved (h, d, kind): rin = h*192 + d*3 + kind.
// Output row r = kind*1024 + h*64 + d.
// Q rows (kind==0) pre-scaled by (1/8)*log2(e) so attention can use exp2.
__global__ void k_cvt_wqkv(const float* __restrict__ w, const float* __restrict__ bsrc,
                           unsigned short* __restrict__ wb, float* __restrict__ br) {
  int t = blockIdx.x * 256 + threadIdx.x;
  int r = t >> 8;                 // 0..3071
  int c = (t & 255) * 4;
  int kind = r >> 10, hd = r & 1023;
  int h = hd >> 6, d = hd & 63;
  int rin = h * 192 + d * 3 + kind;
  float s = (kind == 0) ? 0.125f * 1.4426950408889634f : 1.0f;
  float4 v = *reinterpret_cast<const float4*>(w + (size_t)rin * E_ + c);
  ushort4 o;
  o.x = f2bf(v.x * s); o.y = f2bf(v.y * s); o.z = f2bf(v.z * s); o.w = f2bf(v.w * s);
  *reinterpret_cast<ushort4*>(wb + (size_t)r * E_ + c) = o;
  if (c == 0) br[r] = bsrc[rin] * s;
}

__global__ void k_cvt_wout(const float* __restrict__ w, unsigned short* __restrict__ wb) {
  int t = blockIdx.x * 256 + threadIdx.x;
  int r = t >> 8;
  int c = (t & 255) * 4;
  float4 v = *reinterpret_cast<const float4*>(w + (size_t)r * HD_ + c);
  ushort4 o;
  o.x = f2bf(v.x); o.y = f2bf(v.y); o.z = f2bf(v.z); o.w = f2bf(v.w);
  *reinterpret_cast<ushort4*>(wb + (size_t)r * HD_ + c) = o;
}

// ---------------- GEMM (R9 known-good): 3-buffer counted-vmcnt pipeline ----------------
template <int EPI, int BM>
__global__ __launch_bounds__(256, 2) void k_gemm(
    const unsigned short* __restrict__ A,   // [M][K] bf16
    const unsigned short* __restrict__ W,   // [Nt][K] bf16
    const float* __restrict__ bias,         // [Nt]
    unsigned short* __restrict__ Qo, unsigned short* __restrict__ Ko,
    unsigned short* __restrict__ Vo, float* __restrict__ Fo,
    int M, int Nt, int K)
{
  constexpr int APT = (BM == 128) ? 2 : 1;   // A gld16 per thread per tile
  constexpr int LPI = APT + 2;               // loads per thread per tile
  constexpr int NF  = (BM == 128) ? 4 : 2;   // n-frags per wave
  __shared__ unsigned short As[3][BM * 32];
  __shared__ unsigned short Bs[3][128 * 32];
  const int t = threadIdx.x;
  const int w = t >> 6, l = t & 63, lg = l >> 4, lr = l & 15;
  const int wrow0 = (BM == 128) ? (w >> 1) * 64 : 0;
  const int wcol0 = (BM == 128) ? (w & 1) * 64 : w * 32;
  const int row0 = blockIdx.x * BM, col0 = blockIdx.y * 128;
  const int NT = K >> 5;

  f32x4 acc[4][NF] = {};

  auto stage = [&](int b, int k0) {
#pragma unroll
    for (int c = 0; c < APT; ++c) {
      int ci = w * APT + c;
      int row = ci * 16 + (l >> 2);
      int sub = (l & 3) ^ gswz(row);
      gld16(A + (size_t)(row0 + row) * K + k0 + sub * 8,
            (unsigned short*)&As[b][0] + ci * 512);
    }
#pragma unroll
    for (int c = 0; c < 2; ++c) {
      int ci = w * 2 + c;
      int row = ci * 16 + (l >> 2);
      int sub = (l & 3) ^ gswz(row);
      gld16(W + (size_t)(col0 + row) * K + k0 + sub * 8,
            (unsigned short*)&Bs[b][0] + ci * 512);
    }
  };

  stage(0, 0);
  stage(1, 32);

  for (int kt = 0; kt < NT; ++kt) {
    const int ib = kt % 3;
    if (kt + 2 < NT) stage((kt + 2) % 3, (kt + 2) * 32);
    const int na = NT - 1 - kt;
    if (na >= 2) {
      if constexpr (LPI == 4) asm volatile("s_waitcnt vmcnt(8)" ::: "memory");
      else                    asm volatile("s_waitcnt vmcnt(6)" ::: "memory");
    } else if (na == 1) {
      if constexpr (LPI == 4) asm volatile("s_waitcnt vmcnt(4)" ::: "memory");
      else                    asm volatile("s_waitcnt vmcnt(3)" ::: "memory");
    } else {
      asm volatile("s_waitcnt vmcnt(0)" ::: "memory");
    }
    asm volatile("s_barrier" ::: "memory");

    bf16x8 af[4], bf[NF];
#pragma unroll
    for (int m = 0; m < 4; ++m) {
      int row = wrow0 + m * 16 + lr;
      af[m] = *reinterpret_cast<const bf16x8*>(
          &As[ib][row * 32 + ((lg ^ gswz(row)) * 8)]);
    }
#pragma unroll
    for (int n = 0; n < NF; ++n) {
      int row = wcol0 + n * 16 + lr;
      bf[n] = *reinterpret_cast<const bf16x8*>(
          &Bs[ib][row * 32 + ((lg ^ gswz(row)) * 8)]);
    }
    __builtin_amdgcn_s_setprio(1);
#pragma unroll
    for (int m = 0; m < 4; ++m)
#pragma unroll
      for (int n = 0; n < NF; ++n)
        acc[m][n] = __builtin_amdgcn_mfma_f32_16x16x32_bf16(af[m], bf[n], acc[m][n], 0, 0, 0);
    __builtin_amdgcn_s_setprio(0);

    asm volatile("s_barrier" ::: "memory");
  }

#pragma unroll
  for (int m = 0; m < 4; ++m) {
#pragma unroll
    for (int n = 0; n < NF; ++n) {
      int col = col0 + wcol0 + n * 16 + lr;
      float bb = bias[col];
#pragma unroll
      for (int rr = 0; rr < 4; ++rr) {
        int ro = row0 + wrow0 + m * 16 + lg * 4 + rr;
        float val = acc[m][n][rr] + bb;
        if (EPI == 0) {
          int kind = col >> 10, hd = col & 1023, h = hd >> 6, d = hd & 63;
          int bi = ro >> 11, ni = ro & 2047;     // token -> (b, n)
          unsigned short bv = f2bf(val);
          size_t bh = (size_t)(bi * H_ + h);
          if (kind == 0)      Qo[(bh * N_ + ni) * D_ + d] = bv;
          else if (kind == 1) Ko[(bh * N_ + ni) * D_ + d] = bv;
          else                Vo[bh * (size_t)(D_ * N_) + (size_t)d * N_ + ni] = bv;
        } else {
          Fo[(size_t)ro * HD_ + col] = val;
        }
      }
    }
  }
}

// ---------------- flash attention: 2-state pipeline (S(kt+1) || softmax+PV(kt)) ----------------
// R9 sync skeleton unchanged (3 LDS buffers, stage->vmcnt->barrier->compute->barrier).
// New: S for tile kt+1 is computed at iteration kt, so its 8 independent MFMAs
// shadow tile kt's softmax VALU. Buffers kt (V) and kt+1 (K) are read in the same
// iteration while kt+2 stages into the third buffer - all three distinct mod 3.
// vmcnt(4) now guarantees tile kt+1 is landed (one stage, 4 loads, in flight).
__global__ __launch_bounds__(256, 3) void k_attn(
    const unsigned short* __restrict__ Q,
    const unsigned short* __restrict__ Kg,
    const unsigned short* __restrict__ Vg,
    unsigned short* __restrict__ O,
    unsigned short* __restrict__ Pp,    // [bh][16][128][64] bf16 partial O~
    float* __restrict__ Pml)            // [bh][16][128]  l
{
  static const int u_qt[24] = {15,15,14,13,12,11,10, 9,   8, 7,14, 6,13, 5,12, 4,   8, 0, 9, 1,10, 2,11, 3};
  static const int u_t0[24] = { 0,16, 0, 0, 0, 0, 0, 0,   0, 0,16, 0,16, 0,16, 0,  16, 0,16, 0,16, 0,16, 0};
  static const int u_ps[24] = {14,15,12,10, 8, 6, 4, 2,   0,-1,13,-1,11,-1, 9,-1,   1,-1, 3,-1, 5,-1, 7,-1};

  __shared__ unsigned short Ks[3][64 * 64];   // [kv][k], swizzled rows
  __shared__ unsigned short Vs[3][64 * 64];   // [d][kv], swizzled rows

  const int t = threadIdx.x;
  const int w = t >> 6, l = t & 63;
  const int lq = l & 31;
  const int hi = l >> 5;
  const int bh = blockIdx.x & 31;
  const int u  = blockIdx.x >> 5;
  const int qt = u_qt[u], t0 = u_t0[u], ps = u_ps[u];
  const int q0 = qt * 128;
  const int r0w = q0 + w * 32;
  const int rtop = r0w + 31;
  const bool splitc0 = (ps >= 0) && (t0 == 0);
  const int tendW = splitc0 ? 16 : ((rtop >> 6) + 1);
  const int tendB = splitc0 ? 16 : (((q0 + 127) >> 6) + 1);   // always >= t0+2

  const unsigned short* Qb = Q  + (size_t)bh * (N_ * D_);
  const unsigned short* Kb = Kg + (size_t)bh * (N_ * D_);
  const unsigned short* Vb = Vg + (size_t)bh * (N_ * D_);   // [d][n]

  const int pr  = l >> 3;
  const int pswz = ((l & 7) ^ pr) * 8;
  const unsigned short* KsrcB = Kb + pr * D_ + pswz;
  const unsigned short* VsrcB = Vb + pr * N_ + pswz;

  bf16x8 qf[4];
#pragma unroll
  for (int ks = 0; ks < 4; ++ks)
    qf[ks] = *reinterpret_cast<const bf16x8*>(
        Qb + (size_t)(r0w + lq) * D_ + ks * 16 + hi * 8);

  f32x16 oacc[2] = {};
  float lrun = 0.f;

  auto stage = [&](int b, int kt_) {
    const int kv = kt_ * 64;
#pragma unroll
    for (int c = 0; c < 2; ++c) {
      int cb = w * 2 + c;
      gld16(KsrcB + kv * D_ + cb * 512, (unsigned short*)&Ks[b][0] + cb * 512);
      gld16(VsrcB + kv + cb * 8 * N_,   (unsigned short*)&Vs[b][0] + cb * 512);
    }
  };

  auto read_kf = [&](int b, bf16x8 kf[2][4]) {
#pragma unroll
    for (int ct = 0; ct < 2; ++ct)
#pragma unroll
      for (int ks = 0; ks < 4; ++ks) {
        int row = ct * 32 + lq;
        kf[ct][ks] = *reinterpret_cast<const bf16x8*>(
            &Ks[b][row * 64 + (((ks * 2 + hi) ^ (lq & 7)) * 8)]);
      }
  };

  // ---- prologue: stage t0, t0+1; compute S_cur = S(t0) ----
  stage(0, t0);
  stage(1, t0 + 1);
  asm volatile("s_waitcnt vmcnt(4)" ::: "memory");   // t0 landed, t0+1 in flight
  __syncthreads();

  f32x16 scur[2];
  {
    bf16x8 kf[2][4];
    read_kf(0, kf);
#pragma unroll
    for (int ct = 0; ct < 2; ++ct) {
      f32x16 z = {};
#pragma unroll
      for (int ks = 0; ks < 4; ++ks)
        z = __builtin_amdgcn_mfma_f32_32x32x16_bf16(kf[ct][ks], qf[ks], z, 0, 0, 0);
      scur[ct] = z;
    }
  }

  for (int kt = t0; kt < tendB; ++kt) {
    const int ib  = (kt - t0) % 3;
    const int ib1 = (kt - t0 + 1) % 3;
    // stage kt+2 into buf[(kt-1)%3] - last read in iter kt-1, protected by its
    // trailing barrier.
    if (kt + 2 < tendB) {
      stage((kt - t0 + 2) % 3, kt + 2);
      asm volatile("s_waitcnt vmcnt(4)" ::: "memory");   // kt+1 fully landed
    } else {
      asm volatile("s_waitcnt vmcnt(0)" ::: "memory");
    }
    asm volatile("s_barrier" ::: "memory");              // all waves: kt+1 visible

    // ---- S_next = K(kt+1) Q^T : independent of softmax(kt) below ----
    bf16x8 kf[2][4];
    read_kf(ib1, kf);           // if kt+1 >= tendB this is stale data, never used
    f32x16 snext[2];
#pragma unroll
    for (int ct = 0; ct < 2; ++ct) {
      f32x16 z = {};
#pragma unroll
      for (int ks = 0; ks < 4; ++ks)
        z = __builtin_amdgcn_mfma_f32_32x32x16_bf16(kf[ct][ks], qf[ks], z, 0, 0, 0);
      snext[ct] = z;
    }

    if (kt < tendW) {
      const int kv0 = kt * 64;
      // ---- causal mask on S_cur (diag tile only) ----
      if (kv0 + 63 > r0w) {
        int qrow = r0w + lq;
#pragma unroll
        for (int ct = 0; ct < 2; ++ct)
#pragma unroll
          for (int r = 0; r < 16; ++r) {
            int kv = kv0 + ct * 32 + (r & 3) + 8 * (r >> 2) + 4 * hi;
            if (kv > qrow) scur[ct][r] = -1e30f;
          }
      }

      // ---- softmax without max-tracking: P = exp2(s) ----
      float s16[16];
#pragma unroll
      for (int r = 0; r < 16; ++r) {
        float p0 = exp2f(scur[0][r]);
        float p1 = exp2f(scur[1][r]);
        scur[0][r] = p0; scur[1][r] = p1;
        s16[r] = p0 + p1;
      }
#pragma unroll
      for (int st = 8; st >= 1; st >>= 1)
#pragma unroll
        for (int r = 0; r < 8; ++r)
          if (r < st) s16[r] += s16[r + st];
      lrun += s16[0] + __shfl_xor(s16[0], 32);

      // ---- P -> A-frags in-register ----
      bf16x8 paf[4];
#pragma unroll
      for (int ct = 0; ct < 2; ++ct) {
        unsigned u0 = cvtpk(scur[ct][0],  scur[ct][1]);
        unsigned u1 = cvtpk(scur[ct][2],  scur[ct][3]);
        unsigned u2 = cvtpk(scur[ct][4],  scur[ct][5]);
        unsigned u3 = cvtpk(scur[ct][6],  scur[ct][7]);
        unsigned u4 = cvtpk(scur[ct][8],  scur[ct][9]);
        unsigned u5 = cvtpk(scur[ct][10], scur[ct][11]);
        unsigned u6 = cvtpk(scur[ct][12], scur[ct][13]);
        unsigned u7 = cvtpk(scur[ct][14], scur[ct][15]);
        pl32swap(u0, u2); pl32swap(u1, u3);
        pl32swap(u4, u6); pl32swap(u5, u7);
        union { unsigned uu[4]; bf16x8 v; } c0, c1;
        c0.uu[0] = u0; c0.uu[1] = u1; c0.uu[2] = u2; c0.uu[3] = u3;
        c1.uu[0] = u4; c1.uu[1] = u5; c1.uu[2] = u6; c1.uu[3] = u7;
        paf[ct * 2]     = c0.v;
        paf[ct * 2 + 1] = c1.v;
      }

      // ---- V frags (minimal live range) + PV ----
      bf16x8 vf[2][4];
#pragma unroll
      for (int dt = 0; dt < 2; ++dt)
#pragma unroll
        for (int j = 0; j < 4; ++j) {
          int row = dt * 32 + lq;
          vf[dt][j] = *reinterpret_cast<const bf16x8*>(
              &Vs[ib][row * 64 + (((j * 2 + hi) ^ (lq & 7)) * 8)]);
        }
      __builtin_amdgcn_s_setprio(1);
#pragma unroll
      for (int dt = 0; dt < 2; ++dt)
#pragma unroll
        for (int j = 0; j < 4; ++j)
          oacc[dt] = __builtin_amdgcn_mfma_f32_32x32x16_bf16(paf[j], vf[dt][j], oacc[dt], 0, 0, 0);
      __builtin_amdgcn_s_setprio(0);
    }

    scur[0] = snext[0];
    scur[1] = snext[1];
    asm volatile("s_barrier" ::: "memory");              // gate buffer reuse
  }

  // ---- epilogue ----
  int bi = bh >> 4, h = bh & 15;
  if (ps < 0) {
    float inv = 1.0f / lrun;
    float iv[16];
#pragma unroll
    for (int r = 0; r < 16; ++r)
      iv[r] = __shfl(inv, (r & 3) + 8 * (r >> 2) + 4 * hi);
#pragma unroll
    for (int dt = 0; dt < 2; ++dt)
#pragma unroll
      for (int r = 0; r < 16; ++r) {
        int qr = r0w + (r & 3) + 8 * (r >> 2) + 4 * hi;
        int d = dt * 32 + lq;
        O[((size_t)(bi * N_ + qr) * H_ + h) * D_ + d] = f2bf(oacc[dt][r] * iv[r]);
      }
  } else {
    unsigned short* pb = Pp + (size_t)(bh * 16 + ps) * (128 * 64);
    float* mb = Pml + (size_t)(bh * 16 + ps) * 128;
#pragma unroll
    for (int dt = 0; dt < 2; ++dt)
#pragma unroll
      for (int r = 0; r < 16; ++r) {
        int rloc = w * 32 + (r & 3) + 8 * (r >> 2) + 4 * hi;
        pb[rloc * 64 + dt * 32 + lq] = f2bf(oacc[dt][r]);
      }
    if (l < 32) {
      int rloc = w * 32 + l;
      mb[rloc] = lrun;
    }
  }
}

// ---------------- merge the two kv-chunk partials for q0>=1024 tiles ----------------
__global__ void k_merge(const unsigned short* __restrict__ Pp,
                        const float* __restrict__ Pml,
                        unsigned short* __restrict__ O) {
  int t = blockIdx.x * 256 + threadIdx.x;   // 262144 threads
  int dseg = t & 7;
  int rloc = (t >> 3) & 127;
  int qt8 = (t >> 10) & 7;
  int bh  = t >> 13;
  size_t b0 = (size_t)(bh * 16 + qt8 * 2) * 128 + rloc;
  size_t b1 = b0 + 128;
  bf16x8 o0 = *reinterpret_cast<const bf16x8*>(Pp + b0 * 64 + dseg * 8);
  bf16x8 o1 = *reinterpret_cast<const bf16x8*>(Pp + b1 * 64 + dseg * 8);
  float l0 = Pml[b0], l1 = Pml[b1];
  float inv = 1.0f / (l0 + l1);
  int n = (qt8 + 8) * 128 + rloc;
  int bi = bh >> 4, h = bh & 15;
  unsigned short* op = O + ((size_t)(bi * N_ + n) * H_ + h) * D_ + dseg * 8;
  bf16x8 res;
#pragma unroll
  for (int j = 0; j < 8; ++j)
    res[j] = (short)f2bf((bf2f(o0[j]) + bf2f(o1[j])) * inv);
  *reinterpret_cast<bf16x8*>(op) = res;
}

// ---------------- launch ----------------

extern "C" void kernel_launch(void* const* d_in, const int* in_sizes, int n_in,
                              void* d_out, int out_size, void* d_ws, size_t ws_size,
                              hipStream_t stream) {
  const float* x    = (const float*)d_in[0];
  const float* Wqkv = (const float*)d_in[1];
  const float* bqkv = (const float*)d_in[2];
  const float* Wout = (const float*)d_in[3];
  const float* bout = (const float*)d_in[4];
  float* out = (float*)d_out;

  char* ws = (char*)d_ws;
  unsigned short* xb  = (unsigned short*)ws; ws += (size_t)M_ * E_ * 2;       // 8 MB
  unsigned short* wqb = (unsigned short*)ws; ws += (size_t)NT_ * E_ * 2;      // 6 MB
  float*          bqr = (float*)ws;          ws += 16384;                     // 16 KB
  unsigned short* wob = (unsigned short*)ws; ws += (size_t)E_ * HD_ * 2;      // 2 MB
  unsigned short* Qb  = (unsigned short*)ws; ws += (size_t)M_ * D_ * H_ * 2;  // 8 MB
  unsigned short* Kb  = (unsigned short*)ws; ws += (size_t)M_ * D_ * H_ * 2;  // 8 MB
  unsigned short* Vb  = (unsigned short*)ws; ws += (size_t)M_ * D_ * H_ * 2;  // 8 MB
  unsigned short* ao  = (unsigned short*)ws; ws += (size_t)M_ * HD_ * 2;      // 8 MB

  // attention partials ALIAS xb/wqb: both are dead once k_gemm<0> completes,
  // and the stream serializes gemm0 -> attn -> merge.
  unsigned short* Pp  = xb;            // 32*16*128*64 bf16 = 8 MB
  float*          Pml = (float*)wqb;   // 32*16*128 f32 = 256 KB

  k_cvt_x<<<(M_ * E_) / 4 / 256, 256, 0, stream>>>(x, xb);
  k_cvt_wqkv<<<NT_, 256, 0, stream>>>(Wqkv, bqkv, wqb, bqr);
  k_cvt_wout<<<E_, 256, 0, stream>>>(Wout, wob);

  k_gemm<0, 128><<<dim3(M_ / 128, NT_ / 128), 256, 0, stream>>>(
      xb, wqb, bqr, Qb, Kb, Vb, nullptr, M_, NT_, E_);

  k_attn<<<768, 256, 0, stream>>>(Qb, Kb, Vb, ao, Pp, Pml);
  k_merge<<<1024, 256, 0, stream>>>(Pp, Pml, ao);

  k_gemm<1, 64><<<dim3(M_ / 64, HD_ / 128), 256, 0, stream>>>(
      ao, wob, bout, nullptr, nullptr, nullptr, out, M_, HD_, E_);
}